// Round 17
// baseline (3207.118 us; speedup 1.0000x reference)
//
#include <hip/hip_runtime.h>
#include <math.h>
#include <float.h>

constexpr int NE   = 64;      // experts
constexpr int ND   = 2048;    // hidden dim
constexpr int TOPK = 8;
constexpr int TOKS = 64;      // tokens per block (= lanes)
constexpr int NWV  = 8;       // waves per block
constexpr int BLK  = NWV * 64;// 512 threads
constexpr int EPW  = NE / NWV;// 8 experts per wave
constexpr int KC   = 64;      // k-chunk
constexpr int NCH  = ND / KC; // 32 chunks

// Numerics contract (DO NOT CHANGE — validated in round 11, 237us pass):
// h @ w.T emulating OpenBLAS sgemm fp32: K=2048 in kc panels
// {384,384,384,384,256,256} (chunk-6/6/6/6/4/4 of 64); per C-element per
// panel ONE accumulator, serial fp32 FMA with k strictly ascending; panel
// sums added to C in order (__fadd_rn). Then np ufuncs:
// l = fadd(fmul(raw, cs), cb), fp32, unfused. Rank on l32, ties -> lower
// index. Softmax value outputs fp32 (2% threshold).
__global__ __launch_bounds__(BLK, 2)
void gate_kernel(const float* __restrict__ h, const float* __restrict__ w,
                 const float* __restrict__ cs, const float* __restrict__ cb,
                 float* __restrict__ out, int T)
{
    __shared__ float smem[2 * 4096 + 64];  // h dbuf 2x16KB (+ pinv)
    float* const hbuf = smem;
    float* const sl   = smem;              // epilogue alias (buf0): [e][t]
    float* const pp   = smem + 4096;       // epilogue alias (buf1): [t][e] swz
    float* const pinv = smem + 8192;

    const int tid  = threadIdx.x;
    const int lane = tid & 63;                       // lane = token
    const int wv   = __builtin_amdgcn_readfirstlane(tid >> 6);
    const int t0   = blockIdx.x * TOKS;
    const int e0   = wv * EPW;

    // staging role: thread stages 8 floats of one token row (coalesced)
    const int srow = tid >> 3;        // token row 0..63
    const int sseg = tid & 7;         // 8-float segment 0..7
    const float* hsrc = h + (size_t)(t0 + srow) * ND + sseg * 8;
    // bijective slot swizzle: slot(g,row) = ((g ^ (row&15)) + 4*(row>>4)) & 15
    const int ws0 = (((sseg * 2)     ^ (srow & 15)) + ((srow >> 4) << 2)) & 15;
    const int ws1 = (((sseg * 2 + 1) ^ (srow & 15)) + ((srow >> 4) << 2)) & 15;

    // Opaque zero in a VGPR so w loads stay on the VECTOR path
    // (same-address broadcast global_load_dwordx4, vmcnt-pipelined).
    int lzero;
    asm volatile("v_mov_b32 %0, 0" : "=v"(lzero));
    const float* wr0 = w + (size_t)(e0 + 0) * ND + lzero;
    const float* wr1 = w + (size_t)(e0 + 1) * ND + lzero;
    const float* wr2 = w + (size_t)(e0 + 2) * ND + lzero;
    const float* wr3 = w + (size_t)(e0 + 3) * ND + lzero;
    const float* wr4 = w + (size_t)(e0 + 4) * ND + lzero;
    const float* wr5 = w + (size_t)(e0 + 5) * ND + lzero;
    const float* wr6 = w + (size_t)(e0 + 6) * ND + lzero;
    const float* wr7 = w + (size_t)(e0 + 7) * ND + lzero;

    float C[EPW], a[EPW];
#pragma unroll
    for (int i = 0; i < EPW; ++i) C[i] = 0.f;

    // prologue: stage chunk 0 into buffer 0
    {
        const float4 v0 = *reinterpret_cast<const float4*>(hsrc);
        const float4 v1 = *reinterpret_cast<const float4*>(hsrc + 4);
        *reinterpret_cast<float4*>(&hbuf[srow * 64 + ws0 * 4]) = v0;
        *reinterpret_cast<float4*>(&hbuf[srow * 64 + ws1 * 4]) = v1;
    }
    __syncthreads();

    const int lxor = lane & 15;
    const int ladd = (lane >> 4) << 2;

#pragma unroll 1
    for (int c = 0; c < NCH; ++c) {
        const bool pstart = (c == 0) || (c == 6) || (c == 12) || (c == 18) || (c == 24) || (c == 28);
        const bool pend   = (c == 5) || (c == 11) || (c == 17) || (c == 23) || (c == 27) || (c == 31);
        if (pstart) {
#pragma unroll
            for (int i = 0; i < EPW; ++i) a[i] = 0.f;
        }

        // prefetch next h chunk (coalesced global -> 2 float4 regs)
        float4 nh0, nh1;
        const bool hasn = (c + 1 < NCH);
        if (hasn) {
            nh0 = *reinterpret_cast<const float4*>(hsrc + (c + 1) * KC);
            nh1 = *reinterpret_cast<const float4*>(hsrc + (c + 1) * KC + 4);
        }

        // ---- compute chunk c: serial FMA, k ascending (contract) ----
        const float* hb = &hbuf[(c & 1) * 4096 + lane * 64];
        const int kbase = c * KC;
#pragma unroll
        for (int k4 = 0; k4 < KC / 4; ++k4) {
            const int slot = ((k4 ^ lxor) + ladd) & 15;
            const float4 h4 = *reinterpret_cast<const float4*>(hb + slot * 4);
            const int kk = kbase + k4 * 4;

            const float4 w0 = *reinterpret_cast<const float4*>(wr0 + kk);
            const float4 w1 = *reinterpret_cast<const float4*>(wr1 + kk);
            const float4 w2 = *reinterpret_cast<const float4*>(wr2 + kk);
            const float4 w3 = *reinterpret_cast<const float4*>(wr3 + kk);
            const float4 w4 = *reinterpret_cast<const float4*>(wr4 + kk);
            const float4 w5 = *reinterpret_cast<const float4*>(wr5 + kk);
            const float4 w6 = *reinterpret_cast<const float4*>(wr6 + kk);
            const float4 w7 = *reinterpret_cast<const float4*>(wr7 + kk);

            a[0] = __builtin_fmaf(h4.w, w0.w, __builtin_fmaf(h4.z, w0.z,
                   __builtin_fmaf(h4.y, w0.y, __builtin_fmaf(h4.x, w0.x, a[0]))));
            a[1] = __builtin_fmaf(h4.w, w1.w, __builtin_fmaf(h4.z, w1.z,
                   __builtin_fmaf(h4.y, w1.y, __builtin_fmaf(h4.x, w1.x, a[1]))));
            a[2] = __builtin_fmaf(h4.w, w2.w, __builtin_fmaf(h4.z, w2.z,
                   __builtin_fmaf(h4.y, w2.y, __builtin_fmaf(h4.x, w2.x, a[2]))));
            a[3] = __builtin_fmaf(h4.w, w3.w, __builtin_fmaf(h4.z, w3.z,
                   __builtin_fmaf(h4.y, w3.y, __builtin_fmaf(h4.x, w3.x, a[3]))));
            a[4] = __builtin_fmaf(h4.w, w4.w, __builtin_fmaf(h4.z, w4.z,
                   __builtin_fmaf(h4.y, w4.y, __builtin_fmaf(h4.x, w4.x, a[4]))));
            a[5] = __builtin_fmaf(h4.w, w5.w, __builtin_fmaf(h4.z, w5.z,
                   __builtin_fmaf(h4.y, w5.y, __builtin_fmaf(h4.x, w5.x, a[5]))));
            a[6] = __builtin_fmaf(h4.w, w6.w, __builtin_fmaf(h4.z, w6.z,
                   __builtin_fmaf(h4.y, w6.y, __builtin_fmaf(h4.x, w6.x, a[6]))));
            a[7] = __builtin_fmaf(h4.w, w7.w, __builtin_fmaf(h4.z, w7.z,
                   __builtin_fmaf(h4.y, w7.y, __builtin_fmaf(h4.x, w7.x, a[7]))));
        }

        if (pend) {
#pragma unroll
            for (int i = 0; i < EPW; ++i) C[i] = __fadd_rn(C[i], a[i]);
        }

        // write prefetched chunk into the other buffer (its last readers
        // finished before the previous barrier)
        if (hasn) {
            float* const nb = &hbuf[((c + 1) & 1) * 4096];
            *reinterpret_cast<float4*>(&nb[srow * 64 + ws0 * 4]) = nh0;
            *reinterpret_cast<float4*>(&nb[srow * 64 + ws1 * 4]) = nh1;
        }
        __syncthreads();
    }

    // ---- epilogue (validated R11); hbuf regions reused after barrier ----
#pragma unroll
    for (int i = 0; i < EPW; ++i) {
        const int e = e0 + i;
        // np ufuncs: mul then add, both rounded fp32, no fma contraction
        sl[e * TOKS + lane] = __fadd_rn(__fmul_rn(C[i], cs[e]), cb[e]);
    }
    __syncthreads();

    float* const out_probs = out;                           // T*64
    float* const out_wts   = out + (size_t)T * NE;          // T*8
    float* const out_idx   = out + (size_t)T * (NE + TOPK); // T*8

    if (wv == 0) {
        float l[NE];
#pragma unroll
        for (int e = 0; e < NE; ++e) l[e] = sl[e * TOKS + lane];

        float m = l[0];
#pragma unroll
        for (int e = 1; e < NE; ++e) m = fmaxf(m, l[e]);

        float u[NE];
        float s = 0.f;
#pragma unroll
        for (int e = 0; e < NE; ++e) {
            u[e] = expf(l[e] - m);
            s += u[e];
        }
        const float inv = 1.f / s;
        pinv[lane] = inv;

        // stage unnormalized probs, XOR-swizzled (conflict-free)
#pragma unroll
        for (int e = 0; e < NE; ++e)
            pp[lane * NE + (e ^ (lane & 31))] = u[e];

        // top-8 on l32; strict > insertion, e ascending => ties keep lower index
        float kv[TOPK]; int iv[TOPK];
#pragma unroll
        for (int j = 0; j < TOPK; ++j) { kv[j] = -FLT_MAX; iv[j] = 0; }
#pragma unroll
        for (int e = 0; e < NE; ++e) {
            float v = l[e]; int ix = e;
#pragma unroll
            for (int j = 0; j < TOPK; ++j) {
                const bool gt = v > kv[j];
                const float nv = gt ? kv[j] : v;
                const int   ni = gt ? iv[j] : ix;
                kv[j] = gt ? v  : kv[j];
                iv[j] = gt ? ix : iv[j];
                v = nv; ix = ni;
            }
        }

        float ws[TOPK];
#pragma unroll
        for (int j = 0; j < TOPK; ++j)
            ws[j] = pp[lane * NE + (iv[j] ^ (lane & 31))] * inv;

        const int tok = t0 + lane;
        *reinterpret_cast<float4*>(out_wts + (size_t)tok * TOPK)
            = make_float4(ws[0], ws[1], ws[2], ws[3]);
        *reinterpret_cast<float4*>(out_wts + (size_t)tok * TOPK + 4)
            = make_float4(ws[4], ws[5], ws[6], ws[7]);
        *reinterpret_cast<float4*>(out_idx + (size_t)tok * TOPK)
            = make_float4((float)iv[0], (float)iv[1], (float)iv[2], (float)iv[3]);
        *reinterpret_cast<float4*>(out_idx + (size_t)tok * TOPK + 4)
            = make_float4((float)iv[4], (float)iv[5], (float)iv[6], (float)iv[7]);
    }
    __syncthreads();

    // cooperative coalesced probs store: 4096 floats / 512 threads = 8 each
    {
        const size_t base = (size_t)t0 * NE;
#pragma unroll
        for (int r = 0; r < (TOKS * NE) / BLK; ++r) {
            const int idx = r * BLK + tid;
            const int t = idx >> 6, e = idx & 63;
            out_probs[base + idx] = pp[t * NE + (e ^ (t & 31))] * pinv[t];
        }
    }
}

extern "C" void kernel_launch(void* const* d_in, const int* in_sizes, int n_in,
                              void* d_out, int out_size, void* d_ws, size_t ws_size,
                              hipStream_t stream)
{
    const float* h  = (const float*)d_in[0];
    const float* w  = (const float*)d_in[1];
    const float* cs = (const float*)d_in[2];
    const float* cb = (const float*)d_in[3];
    float* outp = (float*)d_out;
    const int T = in_sizes[0] / ND;   // 16384 tokens

    dim3 grid(T / TOKS);              // 256 blocks (1 per CU)
    dim3 block(BLK);                  // 512 threads, 8 waves
    hipLaunchKernelGGL(gate_kernel, grid, block, 0, stream,
                       h, w, cs, cb, outp, T);
}

// Round 18
// 151.770 us; speedup vs baseline: 21.1314x; 21.1314x over previous
//
#include <hip/hip_runtime.h>
#include <math.h>
#include <float.h>

constexpr int NE   = 64;      // experts
constexpr int ND   = 2048;    // hidden dim
constexpr int TOPK = 8;
constexpr int TOKS = 64;      // tokens per block (= lanes)
constexpr int NWV  = 8;       // waves per block
constexpr int BLK  = NWV * 64;// 512 threads
constexpr int EPW  = NE / NWV;// 8 experts per wave
constexpr int KC   = 64;      // k-chunk
constexpr int NCH  = ND / KC; // 32 chunks
constexpr int HSTR = 65;      // h LDS row stride (+1 pad: conflict-free both ways)

// Numerics contract (DO NOT CHANGE — validated in round 11, 237us pass):
// h @ w.T emulating OpenBLAS sgemm fp32: K=2048 in kc panels
// {384,384,384,384,256,256} (chunks of 64: 6/6/6/6/4/4); per C-element per
// panel ONE accumulator, serial fp32 FMA with k strictly ascending; panel
// sums added to C in order (__fadd_rn). Then np ufuncs:
// l = fadd(fmul(raw, cs), cb), fp32, unfused. Rank on l32, ties -> lower
// index. Softmax value outputs fp32 (2% threshold).
__global__ __launch_bounds__(BLK)
void gate_kernel(const float* __restrict__ h, const float* __restrict__ w,
                 const float* __restrict__ cs, const float* __restrict__ cb,
                 float* __restrict__ out, int T)
{
    __shared__ float hbuf[KC * HSTR];  // 16.6 KB, [k][t], stride 65
    __shared__ float sl[NE * TOKS];    // 16 KB logits [e][t]
    __shared__ float pp[TOKS * NE];    // 16 KB swizzled unnorm probs [t][e]
    __shared__ float pinv[TOKS];

    const int tid  = threadIdx.x;
    const int lane = tid & 63;                       // lane = token
    const int wv   = __builtin_amdgcn_readfirstlane(tid >> 6);
    const int t0   = blockIdx.x * TOKS;
    const int e0   = wv * EPW;

    // staging: thread loads 8 floats of one token row (coalesced global)
    const int srow = tid >> 3;        // token row 0..63
    const int sseg = tid & 7;         // 8-float k segment
    const float* hsrc = h + (size_t)(t0 + srow) * ND + sseg * 8;

    float C[EPW], a[EPW];
#pragma unroll
    for (int i = 0; i < EPW; ++i) C[i] = 0.f;

    // prologue: stage chunk 0
    {
        const float4 v0 = *reinterpret_cast<const float4*>(hsrc);
        const float4 v1 = *reinterpret_cast<const float4*>(hsrc + 4);
        const float vv[8] = {v0.x, v0.y, v0.z, v0.w, v1.x, v1.y, v1.z, v1.w};
#pragma unroll
        for (int j = 0; j < 8; ++j)
            hbuf[(sseg * 8 + j) * HSTR + srow] = vv[j];   // banks spread: free
    }
    __syncthreads();

#pragma unroll 1
    for (int c = 0; c < NCH; ++c) {
        const bool pstart = (c == 0) || (c == 6) || (c == 12) || (c == 18) || (c == 24) || (c == 28);
        const bool pend   = (c == 5) || (c == 11) || (c == 17) || (c == 23) || (c == 27) || (c == 31);
        if (pstart) {
#pragma unroll
            for (int i = 0; i < EPW; ++i) a[i] = 0.f;
        }

        // prefetch next h chunk (coalesced; only 8 VGPRs live through compute)
        float4 n0, n1;
        const bool hasn = (c + 1 < NCH);
        if (hasn) {
            n0 = *reinterpret_cast<const float4*>(hsrc + (c + 1) * KC);
            n1 = *reinterpret_cast<const float4*>(hsrc + (c + 1) * KC + 4);
        }

        // ---- compute chunk c: serial FMA, k ascending (contract) ----
        const int kb = c * KC;
#pragma unroll 2
        for (int k4 = 0; k4 < KC / 4; ++k4) {
            // h from LDS: lane-consecutive dwords, 2-way = free (ds_read2 pairs)
            const float h0 = hbuf[(k4 * 4 + 0) * HSTR + lane];
            const float h1 = hbuf[(k4 * 4 + 1) * HSTR + lane];
            const float h2 = hbuf[(k4 * 4 + 2) * HSTR + lane];
            const float h3 = hbuf[(k4 * 4 + 3) * HSTR + lane];

#pragma unroll
            for (int i = 0; i < EPW; ++i) {
                // wave-uniform w segment -> s_load_dwordx4; FMA reads SGPR
                const float* wp = w + (size_t)(e0 + i) * ND + kb + k4 * 4;
                float t = a[i];
                t = __builtin_fmaf(h0, wp[0], t);
                t = __builtin_fmaf(h1, wp[1], t);
                t = __builtin_fmaf(h2, wp[2], t);
                t = __builtin_fmaf(h3, wp[3], t);
                a[i] = t;
            }
        }

        if (pend) {
#pragma unroll
            for (int i = 0; i < EPW; ++i) C[i] = __fadd_rn(C[i], a[i]);
        }

        __syncthreads();                  // everyone done reading hbuf
        if (hasn) {
            const float vv[8] = {n0.x, n0.y, n0.z, n0.w, n1.x, n1.y, n1.z, n1.w};
#pragma unroll
            for (int j = 0; j < 8; ++j)
                hbuf[(sseg * 8 + j) * HSTR + srow] = vv[j];
        }
        __syncthreads();                  // next chunk staged
    }

    // ---- epilogue (validated R11/R17) ----
#pragma unroll
    for (int i = 0; i < EPW; ++i) {
        const int e = e0 + i;
        // np ufuncs: mul then add, both rounded fp32, no fma contraction
        sl[e * TOKS + lane] = __fadd_rn(__fmul_rn(C[i], cs[e]), cb[e]);
    }
    __syncthreads();

    float* const out_probs = out;                           // T*64
    float* const out_wts   = out + (size_t)T * NE;          // T*8
    float* const out_idx   = out + (size_t)T * (NE + TOPK); // T*8

    if (wv == 0) {
        float l[NE];
#pragma unroll
        for (int e = 0; e < NE; ++e) l[e] = sl[e * TOKS + lane];

        float m = l[0];
#pragma unroll
        for (int e = 1; e < NE; ++e) m = fmaxf(m, l[e]);

        float u[NE];
        float s = 0.f;
#pragma unroll
        for (int e = 0; e < NE; ++e) {
            u[e] = expf(l[e] - m);
            s += u[e];
        }
        const float inv = 1.f / s;
        pinv[lane] = inv;

#pragma unroll
        for (int e = 0; e < NE; ++e)
            pp[lane * NE + (e ^ (lane & 31))] = u[e];

        // top-8 on l32; strict > insertion, e ascending => ties keep lower index
        float kv[TOPK]; int iv[TOPK];
#pragma unroll
        for (int j = 0; j < TOPK; ++j) { kv[j] = -FLT_MAX; iv[j] = 0; }
#pragma unroll
        for (int e = 0; e < NE; ++e) {
            float v = l[e]; int ix = e;
#pragma unroll
            for (int j = 0; j < TOPK; ++j) {
                const bool gt = v > kv[j];
                const float nv = gt ? kv[j] : v;
                const int   ni = gt ? iv[j] : ix;
                kv[j] = gt ? v  : kv[j];
                iv[j] = gt ? ix : iv[j];
                v = nv; ix = ni;
            }
        }

        float ws[TOPK];
#pragma unroll
        for (int j = 0; j < TOPK; ++j)
            ws[j] = pp[lane * NE + (iv[j] ^ (lane & 31))] * inv;

        const int tok = t0 + lane;
        *reinterpret_cast<float4*>(out_wts + (size_t)tok * TOPK)
            = make_float4(ws[0], ws[1], ws[2], ws[3]);
        *reinterpret_cast<float4*>(out_wts + (size_t)tok * TOPK + 4)
            = make_float4(ws[4], ws[5], ws[6], ws[7]);
        *reinterpret_cast<float4*>(out_idx + (size_t)tok * TOPK)
            = make_float4((float)iv[0], (float)iv[1], (float)iv[2], (float)iv[3]);
        *reinterpret_cast<float4*>(out_idx + (size_t)tok * TOPK + 4)
            = make_float4((float)iv[4], (float)iv[5], (float)iv[6], (float)iv[7]);
    }
    __syncthreads();

    // cooperative coalesced probs store: 4096 floats / 512 threads = 8 each
    {
        const size_t base = (size_t)t0 * NE;
#pragma unroll
        for (int r = 0; r < (TOKS * NE) / BLK; ++r) {
            const int idx = r * BLK + tid;
            const int t = idx >> 6, e = idx & 63;
            out_probs[base + idx] = pp[t * NE + (e ^ (t & 31))] * pinv[t];
        }
    }
}

extern "C" void kernel_launch(void* const* d_in, const int* in_sizes, int n_in,
                              void* d_out, int out_size, void* d_ws, size_t ws_size,
                              hipStream_t stream)
{
    const float* h  = (const float*)d_in[0];
    const float* w  = (const float*)d_in[1];
    const float* cs = (const float*)d_in[2];
    const float* cb = (const float*)d_in[3];
    float* outp = (float*)d_out;
    const int T = in_sizes[0] / ND;   // 16384 tokens

    dim3 grid(T / TOKS);              // 256 blocks (1 per CU)
    dim3 block(BLK);                  // 512 threads, 8 waves
    hipLaunchKernelGGL(gate_kernel, grid, block, 0, stream,
                       h, w, cs, cb, outp, T);
}